// Round 1
// 404.238 us; speedup vs baseline: 1.1000x; 1.1000x over previous
//
#include <hip/hip_runtime.h>

typedef unsigned short u16;
typedef __bf16 bf16x8 __attribute__((ext_vector_type(8)));
typedef float   f32x4 __attribute__((ext_vector_type(4)));
typedef unsigned short u16x8 __attribute__((ext_vector_type(8)));

// ---------- helpers ----------
__device__ __forceinline__ u16 f2bf(float f) {
    unsigned int u = __builtin_bit_cast(unsigned int, f);
    u = u + 0x7FFFu + ((u >> 16) & 1u);   // round-to-nearest-even
    return (u16)(u >> 16);
}
__device__ __forceinline__ float bf2f(u16 b) {
    return __builtin_bit_cast(float, ((unsigned int)b) << 16);
}
__device__ __forceinline__ void gload16(const void* g, void* l) {
    __builtin_amdgcn_global_load_lds(
        (__attribute__((address_space(1))) void*)g,
        (__attribute__((address_space(3))) void*)l,
        16, 0, 0);
}

#define S_BARRIER()   asm volatile("s_barrier" ::: "memory")
#define WAIT_VMCNT6() asm volatile("s_waitcnt vmcnt(6)" ::: "memory")

// ---------- kernel 1: fp32 -> bf16 cast (h) ----------
__global__ __launch_bounds__(256) void cvt_bf16(const float* __restrict__ x,
                                                u16* __restrict__ y, int n8) {
    int i = blockIdx.x * 256 + threadIdx.x;
    if (i >= n8) return;
    const f32x4* xp = (const f32x4*)x + (size_t)i * 2;
    f32x4 a = xp[0], b = xp[1];
    u16x8 o;
    o[0]=f2bf(a[0]); o[1]=f2bf(a[1]); o[2]=f2bf(a[2]); o[3]=f2bf(a[3]);
    o[4]=f2bf(b[0]); o[5]=f2bf(b[1]); o[6]=f2bf(b[2]); o[7]=f2bf(b[3]);
    ((u16x8*)y)[i] = o;
}

// ---------- kernel 2: Wq [K][N] fp32 -> WqT [N][K] bf16 ----------
__global__ __launch_bounds__(256) void transpose_cvt(const float* __restrict__ W,
                                                     u16* __restrict__ Wt) {
    __shared__ u16 tile[64][65];
    const int c0 = blockIdx.x * 64;
    const int r0 = blockIdx.y * 64;
    const int col = threadIdx.x & 63;
    const int rb  = (threadIdx.x >> 6) * 16;
    #pragma unroll
    for (int rr = 0; rr < 16; ++rr)
        tile[rb + rr][col] = f2bf(W[(size_t)(r0 + rb + rr) * 1024 + c0 + col]);
    __syncthreads();
    const int k = threadIdx.x & 63;
    #pragma unroll
    for (int rr = 0; rr < 16; ++rr) {
        int n = c0 + rb + rr;
        Wt[(size_t)n * 1024 + r0 + k] = tile[k][rb + rr];
    }
}

// ---------- kernel 3: W2T[b][j][h*64+d] = sum_e M0[b,h,d,e]*Wo[h*64+e][j] ----------
__global__ __launch_bounds__(256) void build_w2t(const float* __restrict__ M0,
                                                 const float* __restrict__ Wo,
                                                 u16* __restrict__ W2T) {
    const int jq = blockIdx.x, h = blockIdx.y, b = blockIdx.z;
    const int tid = threadIdx.x;
    const int j = jq * 256 + tid;
    __shared__ float m0s[64 * 64];
    const float* m0p = M0 + ((size_t)b * 16 + h) * 4096;
    for (int i = tid; i < 4096; i += 256) m0s[i] = m0p[i];
    __syncthreads();
    float wo[64];
    #pragma unroll
    for (int e = 0; e < 64; ++e) wo[e] = Wo[(size_t)(h * 64 + e) * 1024 + j];
    u16* outp = W2T + (size_t)b * 1024 * 1024 + (size_t)j * 1024 + h * 64;
    #pragma unroll 1
    for (int d = 0; d < 64; ++d) {
        float s = 0.f;
        #pragma unroll
        for (int e = 0; e < 64; ++e) s += m0s[d * 64 + e] * wo[e];
        outp[d] = f2bf(s);
    }
}

// ---------- GEMM: 256x256 tile, BK=64, 8-phase schedule (T2+T3+T4+T5) ----------
// C[M,N] = A[M,K] * Bt[N,K]^T, bf16 in, fp32 acc.
// 8 waves (2M x 4N), 512 threads, 128 KiB LDS: lds[buf][slot][8192] u16,
// slot 0=A rows 0..127, 1=A rows 128..255, 2=B rows 0..127, 3=B rows 128..255.
// LDS swizzle (both-sides, rule #21): linear dest for global_load_lds, the
// global SOURCE chunk is pre-permuted chunk^=row&7, reads use
// byte ^= ((byte>>7)&7)<<4 (involution; rows are 128 B) -> conflict-free b128.
// Stage order per tile k: p0:(k+1).A1  p1:(k+2).A0  p2:(k+2).B0  p3:(k+2).B1,
// one s_waitcnt vmcnt(6) per K-tile (3 half-tiles = 6 loads in flight).
// Phase reads: p0: A-quad0(8 b128)+B-half0(4)  p1: B-half1(4)  p2: A-quad1(8)
// p3: none.  B-frags persist across the whole K-tile (no re-reads).
// Per phase: 16 MFMA (one C-quadrant x K=64) wrapped in s_setprio(1/0).
// ACC_SSQ (gemm1): per-row sum-of-squares -> ssq[] (LDS then global atomics).
// HAS_SCALE (gemm2): rows scaled by 1/max(sqrt(ssq[row]),1e-12).
// Grid 512 = 128 m-tiles x 4 n-tiles; xcd=id&7 (HW round-robin), all 4
// n-tiles of an m-tile on one XCD (A panel L2-resident, 512%8==0 bijective).

#define STAGE(GB, SLOT) \
    gload16((GB) + g0, (char*)(SLOT) + d0); \
    gload16((GB) + g1, (char*)(SLOT) + d1);

#define READ_A(SLOT) \
    _Pragma("unroll") for (int f = 0; f < 4; ++f) \
    _Pragma("unroll") for (int kk = 0; kk < 2; ++kk) \
        a[f][kk] = *(const bf16x8*)((const char*)(SLOT) + \
            (((rhA + f * 32) << 7) + (cA ^ (kk << 6))));

#define READ_B(SLOT, GB) \
    _Pragma("unroll") for (int g = 0; g < 2; ++g) \
    _Pragma("unroll") for (int kk = 0; kk < 2; ++kk) \
        b[(GB) + g][kk] = *(const bf16x8*)((const char*)(SLOT) + \
            (((rhB + g * 64) << 7) + (cB ^ (kk << 6))));

#define MFMA_QUAD(FB, GB) \
    __builtin_amdgcn_s_setprio(1); \
    _Pragma("unroll") for (int f = 0; f < 4; ++f) \
    _Pragma("unroll") for (int g = 0; g < 2; ++g) \
    _Pragma("unroll") for (int kk = 0; kk < 2; ++kk) \
        acc[(FB) + f][(GB) + g] = __builtin_amdgcn_mfma_f32_16x16x32_bf16( \
            a[f][kk], b[(GB) + g][kk], acc[(FB) + f][(GB) + g], 0, 0, 0); \
    __builtin_amdgcn_s_setprio(0);

#define TILE_BODY(T, BB) { \
    bf16x8 a[4][2], b[4][2]; \
    /* phase 0 */ \
    READ_A(lds[BB][0]); \
    READ_B(lds[BB][2], 0); \
    if ((T) + 1 < NT) { STAGE(A1p + ((T) + 1) * 64, lds[(BB) ^ 1][1]); } \
    S_BARRIER(); \
    MFMA_QUAD(0, 0); \
    S_BARRIER(); \
    /* phase 1 */ \
    READ_B(lds[BB][3], 2); \
    if ((T) + 2 < NT) { STAGE(A0p + ((T) + 2) * 64, lds[BB][0]); } \
    S_BARRIER(); \
    MFMA_QUAD(0, 2); \
    S_BARRIER(); \
    /* phase 2 */ \
    READ_A(lds[BB][1]); \
    if ((T) + 2 < NT) { STAGE(B0p + ((T) + 2) * 64, lds[BB][2]); } \
    S_BARRIER(); \
    MFMA_QUAD(4, 0); \
    S_BARRIER(); \
    /* phase 3 */ \
    if ((T) + 2 < NT) { STAGE(B1p + ((T) + 2) * 64, lds[BB][3]); } \
    S_BARRIER(); \
    MFMA_QUAD(4, 2); \
    WAIT_VMCNT6(); \
    S_BARRIER(); \
}

template <int ACC_SSQ, int HAS_SCALE, typename CT>
__global__ __launch_bounds__(512) void gemm256_8ph(const u16* __restrict__ A,
                                                   const u16* __restrict__ Bt,
                                                   CT* __restrict__ C,
                                                   float* __restrict__ ssq,
                                                   int M, int N, int K,
                                                   long long bt_batch_stride,
                                                   int rpb_log2) {
    __shared__ u16 lds[2][4][8192];   // 128 KiB
    const int tid  = threadIdx.x;
    const int lane = tid & 63;
    const int w    = tid >> 6;
    const int wm   = w >> 2;          // 0..1
    const int wn   = w & 3;           // 0..3

    // XCD-aware swizzle: 4 n-tiles of an m-tile share one XCD's L2.
    const int id  = blockIdx.x;
    const int xcd = id & 7;
    const int loc = id >> 3;
    const int mpx = (M >> 8) >> 3;            // m-tiles per XCD (16)
    const int mt  = xcd * mpx + (loc >> 2);
    const int ntt = loc & 3;
    const int m0  = mt << 8;
    const int n0  = ntt << 8;

    const u16* Btb = Bt + (size_t)(m0 >> rpb_log2) * (size_t)bt_batch_stride;
    const u16* A0p = A   + (size_t)m0 * K;
    const u16* A1p = A0p + (size_t)128 * K;
    const u16* B0p = Btb + (size_t)n0 * K;
    const u16* B1p = B0p + (size_t)128 * K;

    // staging: thread t loads rows (t>>3) and 64+(t>>3); source chunk
    // pre-swizzled so linear LDS + swizzled read is consistent (involution).
    const int    trow   = tid >> 3;
    const int    tchunk = (tid & 7) ^ (trow & 7);
    const size_t g0 = (size_t)trow * K + (size_t)tchunk * 8;   // u16 elems
    const size_t g1 = g0 + (size_t)64 * K;
    const int    d0 = tid * 16;                                 // bytes
    const int    d1 = d0 + 8192;

    const int NT = K >> 6;    // K-tiles (16); NT even, NT >= 2 assumed

    // per-lane LDS read bases (swizzle XOR is constant per lane: +32/+64 row
    // steps don't change row&7)
    const int rm  = lane & 15;
    const int kqb = (lane >> 4) << 4;                // byte offset of kq
    const int rhA = wm * 16 + rm;
    const int cA  = kqb ^ ((rhA & 7) << 4);
    const int rhB = wn * 16 + rm;
    const int cB  = kqb ^ ((rhB & 7) << 4);

    // ---- prologue: T0 fully + T1.{A0,B0,B1}; vmcnt(6) -> T0 landed ----
    STAGE(A0p + 0, lds[0][0]);
    STAGE(B0p + 0, lds[0][2]);
    STAGE(B1p + 0, lds[0][3]);
    STAGE(A1p + 0, lds[0][1]);
    STAGE(A0p + 64, lds[1][0]);
    STAGE(B0p + 64, lds[1][2]);
    STAGE(B1p + 64, lds[1][3]);
    WAIT_VMCNT6();
    S_BARRIER();

    f32x4 acc[8][4] = {};

    #pragma unroll 1
    for (int T = 0; T < NT; T += 2) {
        TILE_BODY(T, 0);
        TILE_BODY(T + 1, 1);
    }

    // ---- epilogue ----  C/D: col=lane&15, row=(lane>>4)*4+reg [m89]
    __syncthreads();
    float* lred = (float*)&lds[0][0][0];   // 256 floats, LDS reuse
    if constexpr (HAS_SCALE) {
        if (tid < 256) {
            float q = ssq[m0 + tid];
            lred[tid] = 1.0f / fmaxf(sqrtf(q), 1e-12f);
        }
        __syncthreads();
    }
    if constexpr (ACC_SSQ) {
        if (tid < 256) lred[tid] = 0.f;
        __syncthreads();
    }
    const int cn = lane & 15;
    const int rq = (lane >> 4) * 4;
    #pragma unroll
    for (int f = 0; f < 8; ++f) {
        const int rbase = f * 32 + wm * 16 + rq;
        #pragma unroll
        for (int r = 0; r < 4; ++r) {
            const size_t rowoff = (size_t)(m0 + rbase + r) * N;
            float s = 0.f;
            #pragma unroll
            for (int g = 0; g < 4; ++g) {
                float x = acc[f][g][r];
                if constexpr (HAS_SCALE) x *= lred[rbase + r];
                if constexpr (ACC_SSQ) s += x * x;
                const int col = n0 + g * 64 + wn * 16 + cn;
                if constexpr (sizeof(CT) == 2) ((u16*)C)[rowoff + col] = f2bf(x);
                else                           C[rowoff + col] = x;
            }
            if constexpr (ACC_SSQ) {
                s += __shfl_xor(s, 1);
                s += __shfl_xor(s, 2);
                s += __shfl_xor(s, 4);
                s += __shfl_xor(s, 8);
                if (cn == 0) atomicAdd(&lred[rbase + r], s);  // 4 wn-waves/row
            }
        }
    }
    if constexpr (ACC_SSQ) {
        __syncthreads();
        if (tid < 256) atomicAdd(&ssq[m0 + tid], lred[tid]);  // 4 n-blocks/row
    }
}

// ---------- launch ----------
// B=4, S=8192, HID=PROJ=1024, NH=16, HD=64; M = B*S = 32768
// ws usage: 77.7 MiB. hbf lives in d_out's first half (dead after gemm1;
// gemm2 overwrites all of d_out — stream-ordered, safe).
extern "C" void kernel_launch(void* const* d_in, const int* in_sizes, int n_in,
                              void* d_out, int out_size, void* d_ws, size_t ws_size,
                              hipStream_t stream) {
    const float* h  = (const float*)d_in[0];   // [4,8192,1024]
    const float* Wq = (const float*)d_in[1];   // [1024,1024]
    const float* Wo = (const float*)d_in[7];   // [1024,1024]
    const float* M0 = (const float*)d_in[8];   // [4,16,64,64]
    float* out = (float*)d_out;

    char* ws = (char*)d_ws;
    u16*   hbf  = (u16*)d_out;                 // 67,108,864 B (first half of out)
    u16*   P    = (u16*)(ws);                  // 67,108,864 B
    u16*   WqT  = (u16*)(ws + 67108864);       //  2,097,152 B
    u16*   W2T  = (u16*)(ws + 69206016);       //  8,388,608 B
    float* ssq  = (float*)(ws + 77594624);     //    131,072 B  (end: 77,725,696)

    const int M = 32768, N = 1024, K = 1024;

    hipMemsetAsync(ssq, 0, M * sizeof(float), stream);   // graph-capture-safe
    cvt_bf16<<<16384, 256, 0, stream>>>(h, hbf, (M * K) / 8);
    transpose_cvt<<<dim3(16, 16), 256, 0, stream>>>(Wq, WqT);
    build_w2t<<<dim3(4, 16, 4), 256, 0, stream>>>(M0, Wo, W2T);
    // P = h @ Wq (bf16, un-normalized) + per-row ssq via atomics
    gemm256_8ph<1, 0, u16><<<512, 512, 0, stream>>>(
        hbf, WqT, P, ssq, M, N, K, 0, 0);
    // out = (1/max(sqrt(ssq),1e-12))[m] * (P @ W2T[batch]) ; batch = m >> 13
    gemm256_8ph<0, 1, float><<<512, 512, 0, stream>>>(
        P, W2T, out, ssq, M, N, K, (long long)1024 * 1024, 13);
}